// Round 6
// baseline (313.779 us; speedup 1.0000x reference)
//
#include <hip/hip_runtime.h>

// FK_Velocity_Loss: pos_loss = vel_loss = mean((out_fk - gt_fk)^2)
// (gt_prev_pose cancels exactly: (o - p) - (g - p) = o - g)
//
// R6 = R4 layout (4 lanes/chain, DPP quad-broadcast mat-vec, VALU-only) +
//  - exactly-one-wave grid: 2048 blocks x 256 thr, __launch_bounds__(256,8)
//    -> 8 blocks/CU co-resident, no dispatch-wave quantization tail
//  - fused finalize via last-block-done ticket (device-scope fetch_add);
//    4-byte counter zeroed per call with hipMemsetAsync (capturable).

#define N_CHAINS 800000                  // 400000 rows x 2 chains
#define BLOCK 256
#define BLOCKS 2048
#define QSTRIDE (BLOCKS * BLOCK / 4)     // 131072 quads per grid pass
#define ITERS 7                          // ceil(800000 / 131072)
#define MEAN_DIV (400000.0 * 2.0 * 3.0)

// Broadcast lane (quad_base + I) across the quad. DPP quad_perm, VALU-only.
template <int I>
__device__ __forceinline__ float qb(float x) {
    return __builtin_bit_cast(float,
        __builtin_amdgcn_mov_dpp(__builtin_bit_cast(int, x),
                                 I | (I << 2) | (I << 4) | (I << 6),
                                 0xF, 0xF, true));
}

// Lane holds row k of M0..M3. Returns component k of (M0*M1*M2*M3)[:,3],
// computed right-to-left: v = M3[:,3]; v = M2*v; v = M1*v; v = M0*v.
__device__ __forceinline__ float fk_elem(float4 m0, float4 m1, float4 m2, float4 m3) {
    float v = m3.w;
    float v0, v1, v2, v3;
    v0 = qb<0>(v); v1 = qb<1>(v); v2 = qb<2>(v); v3 = qb<3>(v);
    v = m2.x * v0 + m2.y * v1 + m2.z * v2 + m2.w * v3;
    v0 = qb<0>(v); v1 = qb<1>(v); v2 = qb<2>(v); v3 = qb<3>(v);
    v = m1.x * v0 + m1.y * v1 + m1.z * v2 + m1.w * v3;
    v0 = qb<0>(v); v1 = qb<1>(v); v2 = qb<2>(v); v3 = qb<3>(v);
    v = m0.x * v0 + m0.y * v1 + m0.z * v2 + m0.w * v3;
    return v;
}

__global__ __launch_bounds__(BLOCK, 8) void fk_loss_kernel(const float4* __restrict__ o4,
                                                           const float4* __restrict__ g4,
                                                           unsigned* __restrict__ counter,
                                                           float* __restrict__ partial,
                                                           float* __restrict__ out) {
    const int tid = blockIdx.x * BLOCK + threadIdx.x;
    const int k = tid & 3;          // row within quad (quad-uniform q0 below)
    const int q0 = tid >> 2;        // base quad/chain index, 0..131071

    const float4* po = o4 + (size_t)q0 * 16 + k;
    const float4* pg = g4 + (size_t)q0 * 16 + k;
    float4 o0 = po[0], o1 = po[4], o2 = po[8], o3 = po[12];
    float4 g0 = pg[0], g1 = pg[4], g2 = pg[8], g3 = pg[12];

    float ss = 0.0f;
#pragma unroll
    for (int it = 0; it < ITERS; ++it) {
        const int c = q0 + it * QSTRIDE;
        float4 no0, no1, no2, no3, ng0, ng1, ng2, ng3;
        const int cn = q0 + (it + 1) * QSTRIDE;
        if (it + 1 < ITERS && cn < N_CHAINS) {  // issue next-iter loads first
            const size_t off = (size_t)cn * 16 + k;
            const float4* qo = o4 + off;
            const float4* qg = g4 + off;
            no0 = qo[0]; no1 = qo[4]; no2 = qo[8]; no3 = qo[12];
            ng0 = qg[0]; ng1 = qg[4]; ng2 = qg[8]; ng3 = qg[12];
        }
        float fo = fk_elem(o0, o1, o2, o3);
        float fg = fk_elem(g0, g1, g2, g3);
        float d = fo - fg;
        if (k < 3 && c < N_CHAINS) ss += d * d;  // garbage iters masked out
        o0 = no0; o1 = no1; o2 = no2; o3 = no3;
        g0 = ng0; g1 = ng1; g2 = ng2; g3 = ng3;
    }

    // wave64 shuffle reduce, then block reduce
#pragma unroll
    for (int off = 32; off > 0; off >>= 1) ss += __shfl_down(ss, off, 64);
    __shared__ float part[BLOCK / 64];
    __shared__ bool amlast;
    if ((threadIdx.x & 63) == 0) part[threadIdx.x >> 6] = ss;
    __syncthreads();
    if (threadIdx.x == 0) {
        float b = part[0] + part[1] + part[2] + part[3];
        __hip_atomic_store(&partial[blockIdx.x], b, __ATOMIC_RELEASE,
                           __HIP_MEMORY_SCOPE_AGENT);
        unsigned prev = __hip_atomic_fetch_add(counter, 1u, __ATOMIC_ACQ_REL,
                                               __HIP_MEMORY_SCOPE_AGENT);
        amlast = (prev == BLOCKS - 1);
    }
    __syncthreads();

    if (amlast) {  // exactly one block runs this, after all partials are visible
        double s = 0.0;
        for (int i = threadIdx.x; i < BLOCKS; i += BLOCK)
            s += (double)__hip_atomic_load(&partial[i], __ATOMIC_ACQUIRE,
                                           __HIP_MEMORY_SCOPE_AGENT);
        __shared__ double dpart[BLOCK / 64];
#pragma unroll
        for (int off = 32; off > 0; off >>= 1) s += __shfl_down(s, off, 64);
        if ((threadIdx.x & 63) == 0) dpart[threadIdx.x >> 6] = s;
        __syncthreads();
        if (threadIdx.x == 0) {
            double b = dpart[0] + dpart[1] + dpart[2] + dpart[3];
            float v = (float)(b / MEAN_DIV);
            out[0] = v;  // pos_loss
            out[1] = v;  // vel_loss (identical: gt_prev cancels)
        }
    }
}

extern "C" void kernel_launch(void* const* d_in, const int* in_sizes, int n_in,
                              void* d_out, int out_size, void* d_ws, size_t ws_size,
                              hipStream_t stream) {
    const float4* output_pose = (const float4*)d_in[0];
    const float4* gt_pose     = (const float4*)d_in[1];
    // d_in[2] (gt_prev_pose) and d_in[3] (gt_pos) are not needed.
    float* out = (float*)d_out;
    unsigned* counter = (unsigned*)d_ws;                    // 4 B, zeroed below
    float* partial = (float*)((char*)d_ws + 512);           // 2048 floats

    hipMemsetAsync(counter, 0, sizeof(unsigned), stream);   // capturable
    fk_loss_kernel<<<BLOCKS, BLOCK, 0, stream>>>(output_pose, gt_pose,
                                                 counter, partial, out);
}

// Round 7
// 164.735 us; speedup vs baseline: 1.9047x; 1.9047x over previous
//
#include <hip/hip_runtime.h>

// FK_Velocity_Loss: pos_loss = vel_loss = mean((out_fk - gt_fk)^2)
// (gt_prev_pose cancels exactly: (o - p) - (g - p) = o - g)
//
// R7: fully-coalesced global loads (64 consecutive float4 = 1KB per wave
// instruction, the m13 6.3TB/s pattern), staged through per-wave LDS to
// re-layout into the R4 quad scheme (lane = row k of chain q), then the
// proven DPP quad-broadcast mat-vec (VALU-only). No barriers: each wave
// owns its LDS region; same-wave DS ops are in-order.
// Grid: 1250 blocks x 4 waves = 5000 waves x 160 chains = 800000 exact.
// 32KB LDS/block -> 5 blocks/CU -> all blocks co-resident (no dispatch tail).

#define N_CHAINS 800000
#define BLOCK 256
#define BLOCKS 1250
#define ITERS 10                       // 16 chains per wave-iter, 160 per wave
#define MEAN_DIV (400000.0 * 2.0 * 3.0)

// Broadcast lane (quad_base + I) across the quad. DPP quad_perm, VALU-only.
template <int I>
__device__ __forceinline__ float qb(float x) {
    return __builtin_bit_cast(float,
        __builtin_amdgcn_mov_dpp(__builtin_bit_cast(int, x),
                                 I | (I << 2) | (I << 4) | (I << 6),
                                 0xF, 0xF, true));
}

// Lane holds row k of M0..M3. Returns component k of (M0*M1*M2*M3)[:,3],
// computed right-to-left: v = M3[:,3]; v = M2*v; v = M1*v; v = M0*v.
__device__ __forceinline__ float fk_elem(float4 m0, float4 m1, float4 m2, float4 m3) {
    float v = m3.w;
    float v0, v1, v2, v3;
    v0 = qb<0>(v); v1 = qb<1>(v); v2 = qb<2>(v); v3 = qb<3>(v);
    v = m2.x * v0 + m2.y * v1 + m2.z * v2 + m2.w * v3;
    v0 = qb<0>(v); v1 = qb<1>(v); v2 = qb<2>(v); v3 = qb<3>(v);
    v = m1.x * v0 + m1.y * v1 + m1.z * v2 + m1.w * v3;
    v0 = qb<0>(v); v1 = qb<1>(v); v2 = qb<2>(v); v3 = qb<3>(v);
    v = m0.x * v0 + m0.y * v1 + m0.z * v2 + m0.w * v3;
    return v;
}

__global__ __launch_bounds__(BLOCK, 5) void fk_loss_kernel(const float4* __restrict__ o4,
                                                           const float4* __restrict__ g4,
                                                           float* __restrict__ partial) {
    __shared__ float4 lds[4][2][256];           // [wave][o/g][16 chains x 16 f4] = 32KB
    const int wid  = threadIdx.x >> 6;
    const int lane = threadIdx.x & 63;
    const int q = lane >> 2;                    // chain-within-window, 0..15
    const int k = lane & 3;                     // row within matrix
    const int w = blockIdx.x * 4 + wid;         // wave id, 0..4999 (exact)

    float4* Lo = lds[wid][0];
    float4* Lg = lds[wid][1];
    const size_t wbase = (size_t)w * (ITERS * 256);   // float4 index of window

    // prologue: stage iter 0
    float4 nx[8];
#pragma unroll
    for (int t = 0; t < 4; ++t) nx[t]     = o4[wbase + t * 64 + lane];
#pragma unroll
    for (int t = 0; t < 4; ++t) nx[4 + t] = g4[wbase + t * 64 + lane];
#pragma unroll
    for (int t = 0; t < 4; ++t) Lo[t * 64 + lane] = nx[t];
#pragma unroll
    for (int t = 0; t < 4; ++t) Lg[t * 64 + lane] = nx[4 + t];

    float ss = 0.0f;
#pragma unroll 1
    for (int it = 0; it < ITERS; ++it) {
        if (it + 1 < ITERS) {                   // issue next window's loads first
            const size_t b = wbase + (size_t)(it + 1) * 256;
#pragma unroll
            for (int t = 0; t < 4; ++t) nx[t]     = o4[b + t * 64 + lane];
#pragma unroll
            for (int t = 0; t < 4; ++t) nx[4 + t] = g4[b + t * 64 + lane];
        }
        // quad-layout readback: lane = (chain q, row k); matrices j=0..3
        const int ib = q * 16 + k;
        float4 mo0 = Lo[ib], mo1 = Lo[ib + 4], mo2 = Lo[ib + 8], mo3 = Lo[ib + 12];
        float4 mg0 = Lg[ib], mg1 = Lg[ib + 4], mg2 = Lg[ib + 8], mg3 = Lg[ib + 12];
        float fo = fk_elem(mo0, mo1, mo2, mo3);
        float fg = fk_elem(mg0, mg1, mg2, mg3);
        float d = fo - fg;
        if (k < 3) ss += d * d;
        if (it + 1 < ITERS) {                   // stage next window (reads of this
#pragma unroll                                  //  window already consumed above)
            for (int t = 0; t < 4; ++t) Lo[t * 64 + lane] = nx[t];
#pragma unroll
            for (int t = 0; t < 4; ++t) Lg[t * 64 + lane] = nx[4 + t];
        }
    }

    // wave64 shuffle reduce, then block reduce, one store per block
#pragma unroll
    for (int off = 32; off > 0; off >>= 1) ss += __shfl_down(ss, off, 64);
    __shared__ float part[4];
    if ((threadIdx.x & 63) == 0) part[threadIdx.x >> 6] = ss;
    __syncthreads();
    if (threadIdx.x == 0)
        partial[blockIdx.x] = part[0] + part[1] + part[2] + part[3];
}

__global__ __launch_bounds__(BLOCK) void fk_finalize(const float* __restrict__ partial,
                                                     float* __restrict__ out) {
    double s = 0.0;
    for (int i = threadIdx.x; i < BLOCKS; i += BLOCK) s += (double)partial[i];
    __shared__ double dpart[4];
#pragma unroll
    for (int off = 32; off > 0; off >>= 1) s += __shfl_down(s, off, 64);
    if ((threadIdx.x & 63) == 0) dpart[threadIdx.x >> 6] = s;
    __syncthreads();
    if (threadIdx.x == 0) {
        double b = dpart[0] + dpart[1] + dpart[2] + dpart[3];
        float v = (float)(b / MEAN_DIV);
        out[0] = v;  // pos_loss
        out[1] = v;  // vel_loss (identical: gt_prev cancels)
    }
}

extern "C" void kernel_launch(void* const* d_in, const int* in_sizes, int n_in,
                              void* d_out, int out_size, void* d_ws, size_t ws_size,
                              hipStream_t stream) {
    const float4* output_pose = (const float4*)d_in[0];
    const float4* gt_pose     = (const float4*)d_in[1];
    // d_in[2] (gt_prev_pose) and d_in[3] (gt_pos) are not needed.
    float* out = (float*)d_out;
    float* partial = (float*)d_ws;   // BLOCKS floats, fully overwritten each call

    fk_loss_kernel<<<BLOCKS, BLOCK, 0, stream>>>(output_pose, gt_pose, partial);
    fk_finalize<<<1, BLOCK, 0, stream>>>(partial, out);
}